// Round 1
// baseline (2641.105 us; speedup 1.0000x reference)
//
#include <hip/hip_runtime.h>

#define NROWS 65536
#define ADIM 1024
#define CCLS 1000
#define SAUG 2
#define MROWS (NROWS + SAUG*CCLS)   /* 67536 */
#define BM 32
#define BN 256
#define KB 32
#define NEG_INF (-3.0e38f)

// ---------------- histogram of labels ----------------
__global__ void k_hist(const int* __restrict__ tgt, int* __restrict__ cnt){
  int i = blockIdx.x*blockDim.x + threadIdx.x;
  int stride = gridDim.x*blockDim.x;
  for (; i < NROWS; i += stride) atomicAdd(&cnt[tgt[i]], 1);
}

// ---------------- exclusive scan over 1000 counts ----------------
__global__ void k_scan(const int* __restrict__ cnt, int* __restrict__ start){
  __shared__ int s[1024];
  int t = threadIdx.x;
  int v = (t < CCLS) ? cnt[t] : 0;
  s[t] = v;
  __syncthreads();
  for (int off = 1; off < 1024; off <<= 1){
    int u = (t >= off) ? s[t-off] : 0;
    __syncthreads();
    s[t] += u;
    __syncthreads();
  }
  if (t < CCLS) start[t] = s[t] - v;   // exclusive
}

// ---------------- scatter row indices grouped by class ----------------
__global__ void k_scatter(const int* __restrict__ tgt, const int* __restrict__ start,
                          int* __restrict__ pos, int* __restrict__ sorted){
  int i = blockIdx.x*blockDim.x + threadIdx.x;
  int stride = gridDim.x*blockDim.x;
  for (; i < NROWS; i += stride){
    int c = tgt[i];
    int r = atomicAdd(&pos[c], 1);
    sorted[start[c] + r] = i;
  }
}

// ---------------- transpose fc_w [1000][1024] -> wT [1024][1024] (zero-pad) ----
__global__ void k_transpose(const float* __restrict__ w, float* __restrict__ wT){
  __shared__ float tile[32][33];
  int kb = blockIdx.x * 32;
  int cb = blockIdx.y * 32;
  int tx = threadIdx.x, ty = threadIdx.y;
  for (int i = ty; i < 32; i += 8){
    int c = cb + i;
    tile[i][tx] = (c < CCLS) ? w[(size_t)c*ADIM + kb + tx] : 0.f;
  }
  __syncthreads();
  int c = cb + tx;
  for (int i = ty; i < 32; i += 8){
    wT[(size_t)(kb + i)*ADIM + c] = tile[tx][i];
  }
}

// ---------------- per-class stats + augmentation rows ----------------
__global__ void k_stats(const float* __restrict__ x, const int* __restrict__ sorted,
                        const int* __restrict__ cnt, const int* __restrict__ start,
                        const float* __restrict__ amt_p, const float* __restrict__ cov_p,
                        const float* __restrict__ ave_p, const float* __restrict__ eps,
                        float* __restrict__ aug){
  int c = blockIdx.x;
  int t = threadIdx.x;
  int col = t*4;
  int n = cnt[c];
  int st = start[c];
  float s[4] = {0.f,0.f,0.f,0.f}, q[4] = {0.f,0.f,0.f,0.f};
  for (int i = 0; i < n; i++){
    int row = sorted[st + i];
    const float4 v = *(const float4*)(x + (size_t)row*ADIM + col);
    s[0]+=v.x; s[1]+=v.y; s[2]+=v.z; s[3]+=v.w;
    q[0]+=v.x*v.x; q[1]+=v.y*v.y; q[2]+=v.z*v.z; q[3]+=v.w*v.w;
  }
  float cf = (float)n;
  float cc = (n == 0) ? 1.f : cf;
  float wgt = cf / (cf + amt_p[c] + 1e-10f);
  float4 cv = *(const float4*)(cov_p + (size_t)c*ADIM + col);
  float4 av = *(const float4*)(ave_p + (size_t)c*ADIM + col);
  float cvp[4] = {cv.x,cv.y,cv.z,cv.w};
  float avp[4] = {av.x,av.y,av.z,av.w};
  float ncov[4], nave[4];
  #pragma unroll
  for (int j = 0; j < 4; j++){
    float ave = s[j]/cc;
    float var = (q[j] - 2.f*ave*s[j] + cf*ave*ave)/cc;   // == segsum((x-ave)^2)/cc
    if (var <= 0.f) var = 1e-10f;
    float add = wgt*(1.f-wgt)*(avp[j]-ave)*(avp[j]-ave);
    ncov[j] = cvp[j]*(1.f-wgt) + var*wgt + add;
    nave[j] = avp[j]*(1.f-wgt) + ave*wgt;
  }
  #pragma unroll
  for (int s_ = 0; s_ < SAUG; s_++){
    size_t off = ((size_t)(s_*CCLS + c))*ADIM + col;
    const float4 e = *(const float4*)(eps + off);
    float4 o;
    o.x = nave[0] + ncov[0]*e.x;
    o.y = nave[1] + ncov[1]*e.y;
    o.z = nave[2] + ncov[2]*e.z;
    o.w = nave[3] + ncov[3]*e.w;
    *(float4*)(aug + off) = o;
  }
}

// ---------------- fused GEMM + online log-softmax + NLL ----------------
#define FMA_ROW(ai, fc_) \
  acc[ai].x += (fc_)*wv.x; acc[ai].y += (fc_)*wv.y; \
  acc[ai].z += (fc_)*wv.z; acc[ai].w += (fc_)*wv.w;

__global__ __launch_bounds__(256) void k_gemm_loss(
    const float* __restrict__ x, const float* __restrict__ aug,
    const float* __restrict__ wT, const float* __restrict__ fc_b,
    const float* __restrict__ ba, const int* __restrict__ tgt,
    float* __restrict__ loss_acc){
  __shared__ float featT[KB*36];     // [k][row], stride 36 (16B-aligned rows)
  __shared__ float wls[KB*260];      // [k][c], stride 260
  const int tid = threadIdx.x;
  const int lane = tid & 63;
  const int wid = tid >> 6;
  const int row0 = blockIdx.x * BM;
  const int r0 = wid * 8;            // wave owns 8 rows

  int lbl[8];
  #pragma unroll
  for (int i = 0; i < 8; i++){
    int gr = row0 + r0 + i;
    if (gr < NROWS) lbl[i] = tgt[gr];
    else if (gr < MROWS){ int a = gr - NROWS; lbl[i] = (a >= CCLS) ? (a - CCLS) : a; }
    else lbl[i] = -1;
  }
  float m_run[8], l_run[8], lab[8];
  #pragma unroll
  for (int i = 0; i < 8; i++){ m_run[i] = NEG_INF; l_run[i] = 0.f; lab[i] = NEG_INF; }

  const int ld_row = tid >> 3;       // 0..31
  const int ld_q  = tid & 7;         // 0..7
  const int g_row = row0 + ld_row;
  const bool rvalid = (g_row < MROWS);
  const float* rowptr = nullptr;
  if (rvalid) rowptr = (g_row < NROWS) ? (x + (size_t)g_row*ADIM)
                                       : (aug + (size_t)(g_row - NROWS)*ADIM);

  for (int cb_i = 0; cb_i < 4; cb_i++){
    const int cb = cb_i * BN;
    float4 acc[8];
    #pragma unroll
    for (int i = 0; i < 8; i++) acc[i] = make_float4(0.f,0.f,0.f,0.f);

    for (int kc = 0; kc < ADIM/KB; kc++){
      __syncthreads();
      // stage feat tile (transposed) -----------------------------------
      float4 fv = make_float4(0.f,0.f,0.f,0.f);
      if (rvalid) fv = *(const float4*)(rowptr + kc*KB + ld_q*4);
      featT[(ld_q*4+0)*36 + ld_row] = fv.x;
      featT[(ld_q*4+1)*36 + ld_row] = fv.y;
      featT[(ld_q*4+2)*36 + ld_row] = fv.z;
      featT[(ld_q*4+3)*36 + ld_row] = fv.w;
      // stage weight tile [k][c] ---------------------------------------
      const float* wrow = wT + (size_t)(kc*KB + ld_row)*ADIM + cb;
      #pragma unroll
      for (int j = 0; j < 8; j++){
        const float4 wv4 = *(const float4*)(wrow + (ld_q + 8*j)*4);
        *(float4*)(&wls[ld_row*260 + (ld_q + 8*j)*4]) = wv4;
      }
      __syncthreads();
      // 8x4 register micro-tile ----------------------------------------
      #pragma unroll
      for (int k = 0; k < KB; k++){
        const float4 f0 = *(const float4*)(&featT[k*36 + r0]);
        const float4 f1 = *(const float4*)(&featT[k*36 + r0 + 4]);
        const float4 wv = *(const float4*)(&wls[k*260 + lane*4]);
        FMA_ROW(0, f0.x) FMA_ROW(1, f0.y) FMA_ROW(2, f0.z) FMA_ROW(3, f0.w)
        FMA_ROW(4, f1.x) FMA_ROW(5, f1.y) FMA_ROW(6, f1.z) FMA_ROW(7, f1.w)
      }
    }

    // chunk epilogue: bias + online softmax update ---------------------
    const int c0 = cb + lane*4;
    float bias[4]; bool valid[4];
    #pragma unroll
    for (int j = 0; j < 4; j++){
      int c = c0 + j;
      valid[j] = (c < CCLS);
      bias[j] = valid[j] ? (fc_b[c] - ba[c]) : 0.f;
    }
    #pragma unroll
    for (int i = 0; i < 8; i++){
      float lg[4] = {acc[i].x + bias[0], acc[i].y + bias[1],
                     acc[i].z + bias[2], acc[i].w + bias[3]};
      float mx = NEG_INF;
      #pragma unroll
      for (int j = 0; j < 4; j++) if (valid[j]) mx = fmaxf(mx, lg[j]);
      #pragma unroll
      for (int o = 32; o > 0; o >>= 1) mx = fmaxf(mx, __shfl_xor(mx, o));
      float mnew = fmaxf(m_run[i], mx);
      float se = 0.f;
      #pragma unroll
      for (int j = 0; j < 4; j++) if (valid[j]) se += __expf(lg[j] - mnew);
      #pragma unroll
      for (int o = 32; o > 0; o >>= 1) se += __shfl_xor(se, o);
      l_run[i] = l_run[i]*__expf(m_run[i] - mnew) + se;
      m_run[i] = mnew;
      float lv = NEG_INF;
      #pragma unroll
      for (int j = 0; j < 4; j++) if (c0 + j == lbl[i]) lv = lg[j];
      #pragma unroll
      for (int o = 32; o > 0; o >>= 1) lv = fmaxf(lv, __shfl_xor(lv, o));
      lab[i] = fmaxf(lab[i], lv);
    }
  }

  float suml = 0.f;
  #pragma unroll
  for (int i = 0; i < 8; i++){
    int gr = row0 + r0 + i;
    if (gr < MROWS) suml += (m_run[i] + logf(l_run[i])) - lab[i];
  }
  if (lane == 0) atomicAdd(loss_acc, suml);
}

__global__ void k_final(const float* __restrict__ loss_acc, float* __restrict__ out){
  out[0] = loss_acc[0] * (1.0f/(float)MROWS);
}

extern "C" void kernel_launch(void* const* d_in, const int* in_sizes, int n_in,
                              void* d_out, int out_size, void* d_ws, size_t ws_size,
                              hipStream_t stream) {
  const float* x     = (const float*)d_in[0];
  const float* eps   = (const float*)d_in[1];
  const float* fc_w  = (const float*)d_in[2];
  const float* fc_b  = (const float*)d_in[3];
  const float* ba    = (const float*)d_in[4];
  const float* cov_p = (const float*)d_in[5];
  const float* ave_p = (const float*)d_in[6];
  const float* amt_p = (const float*)d_in[7];
  const int*   tgt   = (const int*)d_in[8];
  float* out = (float*)d_out;

  char* ws = (char*)d_ws;
  float* wT    = (float*)(ws);                                  // 4 MB
  float* aug   = (float*)(ws + (4u<<20));                       // 8,192,000 B
  int*   sorted= (int*)(ws + (4u<<20) + 8192000u);              // 262,144 B
  int*   cnt   = (int*)(ws + (4u<<20) + 8192000u + 262144u);
  int*   pos   = cnt + 1024;
  float* loss  = (float*)(pos + 1024);
  int*   start = (int*)(loss + 64);

  hipMemsetAsync(cnt, 0, 4096 + 4096 + 256, stream);            // cnt, pos, loss
  k_hist<<<256, 256, 0, stream>>>(tgt, cnt);
  k_scan<<<1, 1024, 0, stream>>>(cnt, start);
  k_scatter<<<256, 256, 0, stream>>>(tgt, start, pos, sorted);
  k_transpose<<<dim3(32,32), dim3(32,8), 0, stream>>>(fc_w, wT);
  k_stats<<<CCLS, 256, 0, stream>>>(x, sorted, cnt, start, amt_p, cov_p, ave_p, eps, aug);
  k_gemm_loss<<<(MROWS + BM - 1)/BM, 256, 0, stream>>>(x, aug, wT, fc_b, ba, tgt, loss);
  k_final<<<1, 1, 0, stream>>>(loss, out);
}

// Round 2
// 774.033 us; speedup vs baseline: 3.4121x; 3.4121x over previous
//
#include <hip/hip_runtime.h>

#define NROWS 65536
#define ADIM  1024
#define CCLS  1000
#define SAUG  2
#define MROWS (NROWS + SAUG*CCLS)   /* 67536 */
#define MPAD  67584                 /* 528*128 */
#define NPAD  1024
#define NSPLIT 4
#define NEG_INF (-3.0e38f)

typedef __bf16 bf16x8 __attribute__((ext_vector_type(8)));
typedef float  f32x4  __attribute__((ext_vector_type(4)));
typedef unsigned short u16;

__device__ __forceinline__ unsigned pk2bf(float a, float b){
  unsigned ua = __float_as_uint(a), ub = __float_as_uint(b);
  ua = (ua + 0x7FFFu + ((ua>>16)&1u)) >> 16;
  ub = (ub + 0x7FFFu + ((ub>>16)&1u)) >> 16;
  return ua | (ub<<16);
}

// ---------------- histogram of labels ----------------
__global__ void k_hist(const int* __restrict__ tgt, int* __restrict__ cnt){
  int i = blockIdx.x*blockDim.x + threadIdx.x;
  int stride = gridDim.x*blockDim.x;
  for (; i < NROWS; i += stride) atomicAdd(&cnt[tgt[i]], 1);
}

// ---------------- exclusive scan over 1000 counts ----------------
__global__ void k_scan(const int* __restrict__ cnt, int* __restrict__ start){
  __shared__ int s[1024];
  int t = threadIdx.x;
  int v = (t < CCLS) ? cnt[t] : 0;
  s[t] = v;
  __syncthreads();
  for (int off = 1; off < 1024; off <<= 1){
    int u = (t >= off) ? s[t-off] : 0;
    __syncthreads();
    s[t] += u;
    __syncthreads();
  }
  if (t < CCLS) start[t] = s[t] - v;   // exclusive
}

// ---------------- scatter row indices grouped by class ----------------
__global__ void k_scatter(const int* __restrict__ tgt, const int* __restrict__ start,
                          int* __restrict__ pos, int* __restrict__ sorted){
  int i = blockIdx.x*blockDim.x + threadIdx.x;
  int stride = gridDim.x*blockDim.x;
  for (; i < NROWS; i += stride){
    int c = tgt[i];
    int r = atomicAdd(&pos[c], 1);
    sorted[start[c] + r] = i;
  }
}

// ---------------- x rows -> bf16 ----------------
__global__ void k_cvt_x(const float* __restrict__ x, u16* __restrict__ xb){
  size_t i = ((size_t)blockIdx.x*blockDim.x + threadIdx.x)*8;
  float4 a = *(const float4*)(x+i);
  float4 b = *(const float4*)(x+i+4);
  uint4 o;
  o.x = pk2bf(a.x,a.y); o.y = pk2bf(a.z,a.w);
  o.z = pk2bf(b.x,b.y); o.w = pk2bf(b.z,b.w);
  *(uint4*)(xb+i) = o;
}

// ---------------- zero pad rows of xb ----------------
__global__ void k_pad(u16* __restrict__ xb){
  size_t i = ((size_t)blockIdx.x*blockDim.x + threadIdx.x)*8 + (size_t)MROWS*ADIM;
  uint4 z = {0u,0u,0u,0u};
  *(uint4*)(xb+i) = z;
}

// ---------------- fc_w -> bf16 (pad classes to 1024 with zeros) ----------------
__global__ void k_cvt_w(const float* __restrict__ w, u16* __restrict__ wb){
  size_t i = ((size_t)blockIdx.x*blockDim.x + threadIdx.x)*8;
  int row = (int)(i >> 10);
  uint4 o = {0u,0u,0u,0u};
  if (row < CCLS){
    float4 a = *(const float4*)(w+i);
    float4 b = *(const float4*)(w+i+4);
    o.x = pk2bf(a.x,a.y); o.y = pk2bf(a.z,a.w);
    o.z = pk2bf(b.x,b.y); o.w = pk2bf(b.z,b.w);
  }
  *(uint4*)(wb+i) = o;
}

// ---------------- combined bias vector (NEG_INF masks pad classes) ----------------
__global__ void k_bias(const float* __restrict__ fc_b, const float* __restrict__ ba,
                       float* __restrict__ biasv){
  int c = blockIdx.x*blockDim.x + threadIdx.x;
  if (c < NPAD) biasv[c] = (c < CCLS) ? fc_b[c] - ba[c] : NEG_INF;
}

// ---------------- per-class stats + augmentation rows (bf16 into xb) ----------------
__global__ void k_stats(const float* __restrict__ x, const int* __restrict__ sorted,
                        const int* __restrict__ cnt, const int* __restrict__ start,
                        const float* __restrict__ amt_p, const float* __restrict__ cov_p,
                        const float* __restrict__ ave_p, const float* __restrict__ eps,
                        u16* __restrict__ xb){
  int c = blockIdx.x;
  int t = threadIdx.x;
  int col = t*4;
  int n = cnt[c];
  int st = start[c];
  float s[4] = {0.f,0.f,0.f,0.f}, q[4] = {0.f,0.f,0.f,0.f};
  for (int i = 0; i < n; i++){
    int row = sorted[st + i];
    const float4 v = *(const float4*)(x + (size_t)row*ADIM + col);
    s[0]+=v.x; s[1]+=v.y; s[2]+=v.z; s[3]+=v.w;
    q[0]+=v.x*v.x; q[1]+=v.y*v.y; q[2]+=v.z*v.z; q[3]+=v.w*v.w;
  }
  float cf = (float)n;
  float cc = (n == 0) ? 1.f : cf;
  float wgt = cf / (cf + amt_p[c] + 1e-10f);
  float4 cv = *(const float4*)(cov_p + (size_t)c*ADIM + col);
  float4 av = *(const float4*)(ave_p + (size_t)c*ADIM + col);
  float cvp[4] = {cv.x,cv.y,cv.z,cv.w};
  float avp[4] = {av.x,av.y,av.z,av.w};
  float ncov[4], nave[4];
  #pragma unroll
  for (int j = 0; j < 4; j++){
    float ave = s[j]/cc;
    float var = (q[j] - 2.f*ave*s[j] + cf*ave*ave)/cc;
    if (var <= 0.f) var = 1e-10f;
    float add = wgt*(1.f-wgt)*(avp[j]-ave)*(avp[j]-ave);
    ncov[j] = cvp[j]*(1.f-wgt) + var*wgt + add;
    nave[j] = avp[j]*(1.f-wgt) + ave*wgt;
  }
  #pragma unroll
  for (int s_ = 0; s_ < SAUG; s_++){
    size_t eoff = ((size_t)(s_*CCLS + c))*ADIM + col;
    size_t roff = ((size_t)(NROWS + s_*CCLS + c))*ADIM + col;
    const float4 e = *(const float4*)(eps + eoff);
    uint2 o;
    o.x = pk2bf(nave[0]+ncov[0]*e.x, nave[1]+ncov[1]*e.y);
    o.y = pk2bf(nave[2]+ncov[2]*e.z, nave[3]+ncov[3]*e.w);
    *(uint2*)(xb + roff) = o;
  }
}

// ---------------- MFMA GEMM + online softmax partials ----------------
// block: 128 rows x 256 cols (2 chunks of 128); wave w owns rows [w*32, w*32+32)
// grid: (528 row tiles, 4 class splits)
__global__ __launch_bounds__(256,2) void k_gemm_part(
    const u16* __restrict__ xb, const u16* __restrict__ wb,
    const float* __restrict__ biasv, const int* __restrict__ tgt,
    float* __restrict__ pm, float* __restrict__ pl, float* __restrict__ plab){
  __shared__ char smem[16384] __attribute__((aligned(16)));
  char* smA = smem;
  char* smB = smem + 8192;
  const int t = threadIdx.x;
  const int lane = t & 63;
  const int wv = t >> 6;
  const int quad = lane >> 4;
  const int col = lane & 15;
  const int row0 = blockIdx.x * 128;
  const int sp = blockIdx.y;

  int lbl[8];
  #pragma unroll
  for (int i = 0; i < 8; i++){
    int gr = row0 + wv*32 + (i>>2)*16 + quad*4 + (i&3);
    int l = -1;
    if (gr < NROWS) l = tgt[gr];
    else if (gr < MROWS){ int a = gr - NROWS; l = (a < CCLS) ? a : a - CCLS; }
    lbl[i] = l;
  }
  float m_run[8], l_run[8], lab[8];
  #pragma unroll
  for (int i = 0; i < 8; i++){ m_run[i] = NEG_INF; l_run[i] = 0.f; lab[i] = NEG_INF; }

  const u16* ga0 = xb + (size_t)row0*ADIM;

  for (int ci = 0; ci < 2; ci++){
    const int nb = sp*2 + ci;
    const u16* gb0 = wb + (size_t)(nb*128)*ADIM;
    f32x4 acc[2][8];
    const f32x4 z = {0.f,0.f,0.f,0.f};
    #pragma unroll
    for (int sm = 0; sm < 2; sm++)
      #pragma unroll
      for (int sn = 0; sn < 8; sn++) acc[sm][sn] = z;

    for (int kc = 0; kc < ADIM/32; kc++){
      __syncthreads();
      #pragma unroll
      for (int i = 0; i < 2; i++){
        int o = i*4096 + t*16;
        int row = o >> 6;
        int kp  = (o >> 4) & 3;
        const u16* g = ga0 + (size_t)row*ADIM + kc*32 + kp*8;
        __builtin_amdgcn_global_load_lds((const __attribute__((address_space(1))) void*)g,
            (__attribute__((address_space(3))) void*)(smA + i*4096 + wv*1024), 16, 0, 0);
        const u16* g2 = gb0 + (size_t)row*ADIM + kc*32 + kp*8;
        __builtin_amdgcn_global_load_lds((const __attribute__((address_space(1))) void*)g2,
            (__attribute__((address_space(3))) void*)(smB + i*4096 + wv*1024), 16, 0, 0);
      }
      __syncthreads();
      bf16x8 af[2], bfr[8];
      const int kq = quad*16;
      #pragma unroll
      for (int sm = 0; sm < 2; sm++){
        int r = wv*32 + sm*16 + col;
        af[sm] = *(const bf16x8*)(smA + r*64 + kq);
      }
      #pragma unroll
      for (int sn = 0; sn < 8; sn++){
        int n = sn*16 + col;
        bfr[sn] = *(const bf16x8*)(smB + n*64 + kq);
      }
      #pragma unroll
      for (int sm = 0; sm < 2; sm++)
        #pragma unroll
        for (int sn = 0; sn < 8; sn++)
          acc[sm][sn] = __builtin_amdgcn_mfma_f32_16x16x32_bf16(af[sm], bfr[sn], acc[sm][sn], 0, 0, 0);
    }

    // chunk epilogue: bias + online softmax over this 128-col chunk
    float bias[8];
    #pragma unroll
    for (int sn = 0; sn < 8; sn++) bias[sn] = biasv[nb*128 + sn*16 + col];
    #pragma unroll
    for (int i = 0; i < 8; i++){
      const int sm = i>>2, rg = i&3;
      float lg[8];
      float mx = NEG_INF, lv = NEG_INF;
      #pragma unroll
      for (int sn = 0; sn < 8; sn++){
        float v = acc[sm][sn][rg] + bias[sn];
        lg[sn] = v;
        mx = fmaxf(mx, v);
        int c = nb*128 + sn*16 + col;
        lv = (c == lbl[i]) ? v : lv;
      }
      #pragma unroll
      for (int o = 1; o < 16; o <<= 1) mx = fmaxf(mx, __shfl_xor(mx, o));
      float mnew = fmaxf(m_run[i], mx);
      float se = 0.f;
      #pragma unroll
      for (int sn = 0; sn < 8; sn++) se += __expf(lg[sn] - mnew);
      #pragma unroll
      for (int o = 1; o < 16; o <<= 1) se += __shfl_xor(se, o);
      l_run[i] = l_run[i]*__expf(m_run[i] - mnew) + se;
      m_run[i] = mnew;
      #pragma unroll
      for (int o = 1; o < 16; o <<= 1) lv = fmaxf(lv, __shfl_xor(lv, o));
      lab[i] = fmaxf(lab[i], lv);
    }
  }

  if (col == 0){
    #pragma unroll
    for (int i = 0; i < 8; i++){
      int gr = row0 + wv*32 + (i>>2)*16 + quad*4 + (i&3);
      size_t idx = (size_t)sp*MPAD + gr;
      pm[idx]   = m_run[i];
      pl[idx]   = l_run[i];
      plab[idx] = lab[i];
    }
  }
}

// ---------------- merge split partials -> loss ----------------
__global__ void k_merge(const float* __restrict__ pm, const float* __restrict__ pl,
                        const float* __restrict__ plab, float* __restrict__ loss){
  int r = blockIdx.x*256 + threadIdx.x;
  float v = 0.f;
  if (r < MROWS){
    float m = NEG_INF, lb = NEG_INF;
    #pragma unroll
    for (int s = 0; s < NSPLIT; s++){
      m  = fmaxf(m,  pm[(size_t)s*MPAD + r]);
      lb = fmaxf(lb, plab[(size_t)s*MPAD + r]);
    }
    float l = 0.f;
    #pragma unroll
    for (int s = 0; s < NSPLIT; s++)
      l += pl[(size_t)s*MPAD + r]*__expf(pm[(size_t)s*MPAD + r] - m);
    v = m + __logf(l) - lb;
  }
  #pragma unroll
  for (int o = 32; o > 0; o >>= 1) v += __shfl_xor(v, o);
  if ((threadIdx.x & 63) == 0) atomicAdd(loss, v);
}

__global__ void k_final(const float* __restrict__ loss, float* __restrict__ out){
  out[0] = loss[0] * (1.0f/(float)MROWS);
}

extern "C" void kernel_launch(void* const* d_in, const int* in_sizes, int n_in,
                              void* d_out, int out_size, void* d_ws, size_t ws_size,
                              hipStream_t stream) {
  const float* x     = (const float*)d_in[0];
  const float* eps   = (const float*)d_in[1];
  const float* fc_w  = (const float*)d_in[2];
  const float* fc_b  = (const float*)d_in[3];
  const float* ba    = (const float*)d_in[4];
  const float* cov_p = (const float*)d_in[5];
  const float* ave_p = (const float*)d_in[6];
  const float* amt_p = (const float*)d_in[7];
  const int*   tgt   = (const int*)d_in[8];
  float* out = (float*)d_out;

  char* ws = (char*)d_ws;
  u16*   xb    = (u16*)(ws);                         // 138,412,032 B
  u16*   wb    = (u16*)(ws + 138412032u);            // 2,097,152 B
  float* biasv = (float*)(ws + 140509184u);          // 4096 B
  int*   sorted= (int*)(ws + 140513280u);            // 262,144 B
  int*   cnt   = (int*)(ws + 140775424u);            // 4096
  int*   pos   = (int*)(ws + 140779520u);            // 4096
  int*   start = (int*)(ws + 140783616u);            // 4096
  float* loss  = (float*)(ws + 140787712u);          // 4096
  float* pm    = (float*)(ws + 140791808u);          // 1,081,344
  float* pl    = (float*)(ws + 141873152u);          // 1,081,344
  float* plab  = (float*)(ws + 142954496u);          // 1,081,344

  hipMemsetAsync(cnt, 0, 16384, stream);             // cnt, pos, start, loss

  k_hist   <<<256, 256, 0, stream>>>(tgt, cnt);
  k_scan   <<<1, 1024, 0, stream>>>(cnt, start);
  k_scatter<<<256, 256, 0, stream>>>(tgt, start, pos, sorted);
  k_cvt_x  <<<32768, 256, 0, stream>>>(x, xb);
  k_pad    <<<24, 256, 0, stream>>>(xb);
  k_cvt_w  <<<512, 256, 0, stream>>>(fc_w, wb);
  k_bias   <<<4, 256, 0, stream>>>(fc_b, ba, biasv);
  k_stats  <<<CCLS, 256, 0, stream>>>(x, sorted, cnt, start, amt_p, cov_p, ave_p, eps, xb);
  k_gemm_part<<<dim3(528, 4), 256, 0, stream>>>(xb, wb, biasv, tgt, pm, pl, plab);
  k_merge  <<<264, 256, 0, stream>>>(pm, pl, plab, loss);
  k_final  <<<1, 1, 0, stream>>>(loss, out);
}

// Round 3
// 701.052 us; speedup vs baseline: 3.7673x; 1.1041x over previous
//
#include <hip/hip_runtime.h>

#define NROWS 65536
#define ADIM  1024
#define CCLS  1000
#define SAUG  2
#define MROWS (NROWS + SAUG*CCLS)   /* 67536 */
#define MPAD  67584                 /* 528*128 */
#define NPAD  1024
#define NPART 8                     /* 4 col-splits x 2 wave col-halves */
#define NEG_INF (-3.0e38f)

typedef __bf16 bf16x8 __attribute__((ext_vector_type(8)));
typedef float  f32x4  __attribute__((ext_vector_type(4)));
typedef unsigned short u16;

__device__ __forceinline__ unsigned pk2bf(float a, float b){
  unsigned ua = __float_as_uint(a), ub = __float_as_uint(b);
  ua = (ua + 0x7FFFu + ((ua>>16)&1u)) >> 16;
  ub = (ub + 0x7FFFu + ((ub>>16)&1u)) >> 16;
  return ua | (ub<<16);
}
__device__ __forceinline__ float bflo(unsigned u){ return __uint_as_float((u & 0xFFFFu) << 16); }
__device__ __forceinline__ float bfhi(unsigned u){ return __uint_as_float(u & 0xFFFF0000u); }

// ---------------- histogram of labels ----------------
__global__ void k_hist(const int* __restrict__ tgt, int* __restrict__ cnt){
  int i = blockIdx.x*blockDim.x + threadIdx.x;
  int stride = gridDim.x*blockDim.x;
  for (; i < NROWS; i += stride) atomicAdd(&cnt[tgt[i]], 1);
}

// ---------------- exclusive scan over 1000 counts ----------------
__global__ void k_scan(const int* __restrict__ cnt, int* __restrict__ start){
  __shared__ int s[1024];
  int t = threadIdx.x;
  int v = (t < CCLS) ? cnt[t] : 0;
  s[t] = v;
  __syncthreads();
  for (int off = 1; off < 1024; off <<= 1){
    int u = (t >= off) ? s[t-off] : 0;
    __syncthreads();
    s[t] += u;
    __syncthreads();
  }
  if (t < CCLS) start[t] = s[t] - v;   // exclusive
}

// ---------------- scatter row indices grouped by class ----------------
__global__ void k_scatter(const int* __restrict__ tgt, const int* __restrict__ start,
                          int* __restrict__ pos, int* __restrict__ sorted){
  int i = blockIdx.x*blockDim.x + threadIdx.x;
  int stride = gridDim.x*blockDim.x;
  for (; i < NROWS; i += stride){
    int c = tgt[i];
    int r = atomicAdd(&pos[c], 1);
    sorted[start[c] + r] = i;
  }
}

// ---------------- x rows -> bf16 ----------------
__global__ void k_cvt_x(const float* __restrict__ x, u16* __restrict__ xb){
  size_t i = ((size_t)blockIdx.x*blockDim.x + threadIdx.x)*8;
  float4 a = *(const float4*)(x+i);
  float4 b = *(const float4*)(x+i+4);
  uint4 o;
  o.x = pk2bf(a.x,a.y); o.y = pk2bf(a.z,a.w);
  o.z = pk2bf(b.x,b.y); o.w = pk2bf(b.z,b.w);
  *(uint4*)(xb+i) = o;
}

// ---------------- zero pad tail rows of xb ----------------
__global__ void k_pad(u16* __restrict__ xb){
  size_t i = ((size_t)blockIdx.x*blockDim.x + threadIdx.x)*8 + (size_t)MROWS*ADIM;
  uint4 z = {0u,0u,0u,0u};
  *(uint4*)(xb+i) = z;
}

// ---------------- fc_w -> bf16 (pad classes to 1024 with zeros) ----------------
__global__ void k_cvt_w(const float* __restrict__ w, u16* __restrict__ wb){
  size_t i = ((size_t)blockIdx.x*blockDim.x + threadIdx.x)*8;
  int row = (int)(i >> 10);
  uint4 o = {0u,0u,0u,0u};
  if (row < CCLS){
    float4 a = *(const float4*)(w+i);
    float4 b = *(const float4*)(w+i+4);
    o.x = pk2bf(a.x,a.y); o.y = pk2bf(a.z,a.w);
    o.z = pk2bf(b.x,b.y); o.w = pk2bf(b.z,b.w);
  }
  *(uint4*)(wb+i) = o;
}

// ---------------- combined bias (NEG_INF masks pad classes) ----------------
__global__ void k_bias(const float* __restrict__ fc_b, const float* __restrict__ ba,
                       float* __restrict__ biasv){
  int c = blockIdx.x*blockDim.x + threadIdx.x;
  if (c < NPAD) biasv[c] = (c < CCLS) ? fc_b[c] - ba[c] : NEG_INF;
}

// ---------------- per-class stats + augmentation rows (reads/writes bf16 xb) ----
__global__ void k_stats(const u16* __restrict__ xb_in, const int* __restrict__ sorted,
                        const int* __restrict__ cnt, const int* __restrict__ start,
                        const float* __restrict__ amt_p, const float* __restrict__ cov_p,
                        const float* __restrict__ ave_p, const float* __restrict__ eps,
                        u16* __restrict__ xb){
  int c = blockIdx.x;
  int t = threadIdx.x;
  int col = t*4;
  int n = cnt[c];
  int st = start[c];
  float s[4] = {0.f,0.f,0.f,0.f}, q[4] = {0.f,0.f,0.f,0.f};
  for (int i = 0; i < n; i++){
    int row = sorted[st + i];
    const uint2 uv = *(const uint2*)(xb_in + (size_t)row*ADIM + col);
    float v0 = bflo(uv.x), v1 = bfhi(uv.x), v2 = bflo(uv.y), v3 = bfhi(uv.y);
    s[0]+=v0; s[1]+=v1; s[2]+=v2; s[3]+=v3;
    q[0]+=v0*v0; q[1]+=v1*v1; q[2]+=v2*v2; q[3]+=v3*v3;
  }
  float cf = (float)n;
  float cc = (n == 0) ? 1.f : cf;
  float wgt = cf / (cf + amt_p[c] + 1e-10f);
  float4 cv = *(const float4*)(cov_p + (size_t)c*ADIM + col);
  float4 av = *(const float4*)(ave_p + (size_t)c*ADIM + col);
  float cvp[4] = {cv.x,cv.y,cv.z,cv.w};
  float avp[4] = {av.x,av.y,av.z,av.w};
  float ncov[4], nave[4];
  #pragma unroll
  for (int j = 0; j < 4; j++){
    float ave = s[j]/cc;
    float var = (q[j] - 2.f*ave*s[j] + cf*ave*ave)/cc;
    if (var <= 0.f) var = 1e-10f;
    float add = wgt*(1.f-wgt)*(avp[j]-ave)*(avp[j]-ave);
    ncov[j] = cvp[j]*(1.f-wgt) + var*wgt + add;
    nave[j] = avp[j]*(1.f-wgt) + ave*wgt;
  }
  #pragma unroll
  for (int s_ = 0; s_ < SAUG; s_++){
    size_t eoff = ((size_t)(s_*CCLS + c))*ADIM + col;
    size_t roff = ((size_t)(NROWS + s_*CCLS + c))*ADIM + col;
    const float4 e = *(const float4*)(eps + eoff);
    uint2 o;
    o.x = pk2bf(nave[0]+ncov[0]*e.x, nave[1]+ncov[1]*e.y);
    o.y = pk2bf(nave[2]+ncov[2]*e.z, nave[3]+ncov[3]*e.w);
    *(uint2*)(xb + roff) = o;
  }
}

// ---------------- MFMA GEMM + softmax partials ----------------
// block: 128 rows x 256 cols; wave (rh,ch) owns 64 rows x 128 cols
// grid: (4 col-splits [fast], 528 row tiles) -> splits of a tile adjacent => L3 reuse
__global__ __launch_bounds__(256,2) void k_gemm_part(
    const u16* __restrict__ xb, const u16* __restrict__ wb,
    const float* __restrict__ biasv, const int* __restrict__ tgt,
    float* __restrict__ pm, float* __restrict__ pl, float* __restrict__ plab){
  __shared__ char smem[24576] __attribute__((aligned(16)));
  char* smA = smem;           // 128 rows x 32k bf16, 64 B/row
  char* smB = smem + 8192;    // 256 cols x 32k bf16, 64 B/col
  const int t = threadIdx.x;
  const int lane = t & 63;
  const int wv = t >> 6;
  const int rh = wv & 1;      // row half (64 rows)
  const int ch = wv >> 1;     // col half (128 cols)
  const int quad = lane >> 4;
  const int col = lane & 15;
  const int row0 = blockIdx.y * 128;
  const int sp = blockIdx.x;

  f32x4 acc[4][8];
  const f32x4 z = {0.f,0.f,0.f,0.f};
  #pragma unroll
  for (int sm = 0; sm < 4; sm++)
    #pragma unroll
    for (int sn = 0; sn < 8; sn++) acc[sm][sn] = z;

  const u16* ga = xb + (size_t)row0*ADIM;
  const u16* gb = wb + (size_t)(sp*256)*ADIM;

  for (int kc = 0; kc < ADIM/32; kc++){
    __syncthreads();
    // stage A: 8 KB (wave wv -> rows [wv*32, wv*32+32))
    #pragma unroll
    for (int i = 0; i < 2; i++){
      int o = wv*2048 + i*1024 + lane*16;
      const u16* g = ga + (size_t)(o>>6)*ADIM + kc*32 + ((o>>4)&3)*8;
      __builtin_amdgcn_global_load_lds((const __attribute__((address_space(1))) void*)g,
          (__attribute__((address_space(3))) void*)(smA + wv*2048 + i*1024), 16, 0, 0);
    }
    // stage B: 16 KB (wave wv -> cols [wv*64, wv*64+64))
    #pragma unroll
    for (int i = 0; i < 4; i++){
      int o = wv*4096 + i*1024 + lane*16;
      const u16* g = gb + (size_t)(o>>6)*ADIM + kc*32 + ((o>>4)&3)*8;
      __builtin_amdgcn_global_load_lds((const __attribute__((address_space(1))) void*)g,
          (__attribute__((address_space(3))) void*)(smB + wv*4096 + i*1024), 16, 0, 0);
    }
    __syncthreads();
    bf16x8 af[4], bfr[8];
    const int kq = quad*16;
    #pragma unroll
    for (int sm = 0; sm < 4; sm++){
      int r = rh*64 + sm*16 + col;
      af[sm] = *(const bf16x8*)(smA + r*64 + kq);
    }
    #pragma unroll
    for (int sn = 0; sn < 8; sn++){
      int n = ch*128 + sn*16 + col;
      bfr[sn] = *(const bf16x8*)(smB + n*64 + kq);
    }
    #pragma unroll
    for (int sm = 0; sm < 4; sm++)
      #pragma unroll
      for (int sn = 0; sn < 8; sn++)
        acc[sm][sn] = __builtin_amdgcn_mfma_f32_16x16x32_bf16(af[sm], bfr[sn], acc[sm][sn], 0, 0, 0);
  }

  // epilogue: bias + per-row max / expsum / label-logit over this 128-col slice
  float bias[8];
  #pragma unroll
  for (int sn = 0; sn < 8; sn++) bias[sn] = biasv[sp*256 + ch*128 + sn*16 + col];
  #pragma unroll
  for (int i = 0; i < 16; i++){
    const int sm = i>>2, rg = i&3;
    const int gr = row0 + rh*64 + sm*16 + quad*4 + rg;
    int lbl = -1;
    if (gr < NROWS) lbl = tgt[gr];
    else if (gr < MROWS){ int a = gr - NROWS; lbl = (a < CCLS) ? a : a - CCLS; }
    float lg[8];
    float mx = NEG_INF, lv = NEG_INF;
    #pragma unroll
    for (int sn = 0; sn < 8; sn++){
      float v = acc[sm][sn][rg] + bias[sn];
      lg[sn] = v;
      mx = fmaxf(mx, v);
      int c = sp*256 + ch*128 + sn*16 + col;
      lv = (c == lbl) ? v : lv;
    }
    #pragma unroll
    for (int o = 1; o < 16; o <<= 1) mx = fmaxf(mx, __shfl_xor(mx, o));
    float se = 0.f;
    #pragma unroll
    for (int sn = 0; sn < 8; sn++) se += __expf(lg[sn] - mx);
    #pragma unroll
    for (int o = 1; o < 16; o <<= 1) se += __shfl_xor(se, o);
    #pragma unroll
    for (int o = 1; o < 16; o <<= 1) lv = fmaxf(lv, __shfl_xor(lv, o));
    if (col == 0){
      size_t idx = (size_t)(sp*2 + ch)*MPAD + gr;
      pm[idx]   = mx;
      pl[idx]   = se;
      plab[idx] = lv;
    }
  }
}

// ---------------- merge 8 partials -> loss (scaled, atomic into out) ----------------
__global__ void k_merge(const float* __restrict__ pm, const float* __restrict__ pl,
                        const float* __restrict__ plab, float* __restrict__ out){
  int r = blockIdx.x*256 + threadIdx.x;
  float v = 0.f;
  if (r < MROWS){
    float m = NEG_INF, lb = NEG_INF;
    #pragma unroll
    for (int s = 0; s < NPART; s++){
      m  = fmaxf(m,  pm[(size_t)s*MPAD + r]);
      lb = fmaxf(lb, plab[(size_t)s*MPAD + r]);
    }
    float l = 0.f;
    #pragma unroll
    for (int s = 0; s < NPART; s++)
      l += pl[(size_t)s*MPAD + r]*__expf(pm[(size_t)s*MPAD + r] - m);
    v = (m + __logf(l) - lb) * (1.0f/(float)MROWS);
  }
  #pragma unroll
  for (int o = 32; o > 0; o >>= 1) v += __shfl_xor(v, o);
  if ((threadIdx.x & 63) == 0) atomicAdd(out, v);
}

extern "C" void kernel_launch(void* const* d_in, const int* in_sizes, int n_in,
                              void* d_out, int out_size, void* d_ws, size_t ws_size,
                              hipStream_t stream) {
  const float* x     = (const float*)d_in[0];
  const float* eps   = (const float*)d_in[1];
  const float* fc_w  = (const float*)d_in[2];
  const float* fc_b  = (const float*)d_in[3];
  const float* ba    = (const float*)d_in[4];
  const float* cov_p = (const float*)d_in[5];
  const float* ave_p = (const float*)d_in[6];
  const float* amt_p = (const float*)d_in[7];
  const int*   tgt   = (const int*)d_in[8];
  float* out = (float*)d_out;

  char* ws = (char*)d_ws;
  u16*   xb    = (u16*)(ws);                         // 138,412,032 B
  u16*   wb    = (u16*)(ws + 138412032u);            // 2,097,152 B
  float* biasv = (float*)(ws + 140509184u);          // 4096 B
  int*   sorted= (int*)(ws + 140513280u);            // 262,144 B
  int*   cnt   = (int*)(ws + 140775424u);            // 4096
  int*   pos   = (int*)(ws + 140779520u);            // 4096
  int*   start = (int*)(ws + 140783616u);            // 4096
  float* pm    = (float*)(ws + 140787712u);          // 2,162,688
  float* pl    = (float*)(ws + 142950400u);          // 2,162,688
  float* plab  = (float*)(ws + 145113088u);          // 2,162,688

  hipMemsetAsync(cnt, 0, 12288, stream);             // cnt, pos, start
  hipMemsetAsync(out, 0, sizeof(float), stream);

  k_hist   <<<256, 256, 0, stream>>>(tgt, cnt);
  k_scan   <<<1, 1024, 0, stream>>>(cnt, start);
  k_scatter<<<256, 256, 0, stream>>>(tgt, start, pos, sorted);
  k_cvt_x  <<<32768, 256, 0, stream>>>(x, xb);
  k_pad    <<<24, 256, 0, stream>>>(xb);
  k_cvt_w  <<<512, 256, 0, stream>>>(fc_w, wb);
  k_bias   <<<4, 256, 0, stream>>>(fc_b, ba, biasv);
  k_stats  <<<CCLS, 256, 0, stream>>>(xb, sorted, cnt, start, amt_p, cov_p, ave_p, eps, xb);
  k_gemm_part<<<dim3(4, 528), 256, 0, stream>>>(xb, wb, biasv, tgt, pm, pl, plab);
  k_merge  <<<264, 256, 0, stream>>>(pm, pl, plab, out);
}